// Round 4
// baseline (257.235 us; speedup 1.0000x reference)
//
#include <hip/hip_runtime.h>
#include <hip/hip_bf16.h>

// SingleHeadAttention: embedded [4,4096,1024] f32; Wk/Wq/Wv [128,1024] f32.
// out = causal_softmax((emb Wq^T)(emb Wk^T)^T / sqrt(128)) (emb Wv^T), f32.
//
// R4 = R3 with the cvt_pkrtz type error fixed (plain _Float16 casts).
//  K0 wconv: W f32 -> bf16 [384][1024] (Wq prescaled by log2e/sqrt(128)).
//  K1 qkv:   GEMM 16384x384x1024, 32 rows/block, reg-prefetch pipelined A-chunks,
//            B direct from L2-resident bf16 W. K,Q bf16; V^T stored f16.
//  K2 attn:  NO-LDS, NO-BARRIER flash attention. S^T = K·Q^T via 16x16x32_bf16
//            (C-layout: col=q=l16, row=key=quad*4+r). P^T is then directly the
//            B-frag of mfma_f32_16x16x16f16 -> O^T = V^T·P^T from registers.
//            K/V^T fragments read straight from L2-resident global. Split-K=4.
//  K3 merge: combine split partials (log2-domain m), normalize, f32 out.
// Layout facts (R2-verified on HW): mfma D col(lane&15) = B's n, row(quad*4+reg)
// = A's m; A/B frag: index=lane&15, k=quad*8+j (K=32) / quad*4+j (K=16).

#define SEQ 4096
#define BATCH 4
#define HS 128

typedef unsigned short u16;
typedef __bf16 bf16x8 __attribute__((ext_vector_type(8)));
typedef _Float16 f16x4 __attribute__((ext_vector_type(4)));
typedef float f32x4 __attribute__((ext_vector_type(4)));

__device__ __forceinline__ u16 f2bf(float f) {
    union { float f; unsigned u; } v; v.f = f;
    unsigned u = v.u;
    return (u16)((u + 0x7FFFu + ((u >> 16) & 1u)) >> 16);  // RNE, finite
}
__device__ __forceinline__ float bf2f(u16 u) {
    union { unsigned u; float f; } v; v.u = ((unsigned)u) << 16; return v.f;
}
__device__ __forceinline__ u16 f2h(float f) {
    union { _Float16 h; u16 u; } v; v.h = (_Float16)f; return v.u;
}

// ---------------- K0: W conversion ----------------
// Wbf[384][1024]: rows 0-127 Wk, 128-255 Wq * log2e/sqrt(128), 256-383 Wv.
__global__ __launch_bounds__(256) void wconv_kernel(
    const float* __restrict__ Wk, const float* __restrict__ Wq,
    const float* __restrict__ Wv, u16* __restrict__ Wbf)
{
    const int row = blockIdx.x;
    const float* src = (row < 128) ? Wk : ((row < 256) ? Wq : Wv);
    const float scale = (row >= 128 && row < 256)
        ? 0.08838834764831845f * 1.4426950408889634f : 1.0f;
    const int t = threadIdx.x;
    const float4 v = *(const float4*)&src[(size_t)(row & 127) * 1024 + t * 4];
    ushort4 o;
    o.x = f2bf(v.x * scale); o.y = f2bf(v.y * scale);
    o.z = f2bf(v.z * scale); o.w = f2bf(v.w * scale);
    *(ushort4*)&Wbf[(size_t)row * 1024 + t * 4] = o;
}

// ---------------- K1: QKV projection ----------------
// grid 512 x 256. Block: 32 emb rows x 384 cols; wave w: cols w*96..+95.
// A-chunk register prefetch pipeline hides emb load latency across barriers.
__global__ __launch_bounds__(256, 2) void qkv_kernel(
    const float* __restrict__ emb, const u16* __restrict__ Wbf,
    u16* __restrict__ Qws, u16* __restrict__ Kws, u16* __restrict__ Vtws)
{
    __shared__ u16 sE[32][72];

    const int tid  = threadIdx.x;
    const int wv   = tid >> 6;
    const int lane = tid & 63;
    const int quad = lane >> 4;
    const int l16  = lane & 15;
    const int R0   = blockIdx.x * 32;
    const int NC   = wv * 96;

    f32x4 acc[2][6];
    #pragma unroll
    for (int rg = 0; rg < 2; rg++)
        #pragma unroll
        for (int nt = 0; nt < 6; nt++) acc[rg][nt] = (f32x4){0.f, 0.f, 0.f, 0.f};

    // prefetch chunk 0 into registers
    const int prow = tid >> 4, pc4 = tid & 15;
    const int prow1 = (tid + 256) >> 4, pc41 = (tid + 256) & 15;
    float4 pre0 = *(const float4*)&emb[(size_t)(R0 + prow) * 1024 + pc4 * 4];
    float4 pre1 = *(const float4*)&emb[(size_t)(R0 + prow1) * 1024 + pc41 * 4];

    for (int kc = 0; kc < 1024; kc += 64) {
        __syncthreads();
        {
            ushort4 o;
            o.x = f2bf(pre0.x); o.y = f2bf(pre0.y); o.z = f2bf(pre0.z); o.w = f2bf(pre0.w);
            *(ushort4*)&sE[prow][pc4 * 4] = o;
            o.x = f2bf(pre1.x); o.y = f2bf(pre1.y); o.z = f2bf(pre1.z); o.w = f2bf(pre1.w);
            *(ushort4*)&sE[prow1][pc41 * 4] = o;
        }
        __syncthreads();
        if (kc + 64 < 1024) {   // prefetch next chunk (in flight during compute)
            pre0 = *(const float4*)&emb[(size_t)(R0 + prow) * 1024 + kc + 64 + pc4 * 4];
            pre1 = *(const float4*)&emb[(size_t)(R0 + prow1) * 1024 + kc + 64 + pc41 * 4];
        }

        bf16x8 a[2][2];
        #pragma unroll
        for (int rg = 0; rg < 2; rg++)
            #pragma unroll
            for (int kf = 0; kf < 2; kf++)
                a[rg][kf] = *(const bf16x8*)&sE[rg * 16 + l16][kf * 32 + quad * 8];

        #pragma unroll
        for (int nt = 0; nt < 6; nt++) {
            const u16* wb = &Wbf[(size_t)(NC + nt * 16 + l16) * 1024 + kc];
            const bf16x8 b0 = *(const bf16x8*)&wb[quad * 8];
            const bf16x8 b1 = *(const bf16x8*)&wb[32 + quad * 8];
            #pragma unroll
            for (int rg = 0; rg < 2; rg++) {
                acc[rg][nt] = __builtin_amdgcn_mfma_f32_16x16x32_bf16(a[rg][0], b0, acc[rg][nt], 0, 0, 0);
                acc[rg][nt] = __builtin_amdgcn_mfma_f32_16x16x32_bf16(a[rg][1], b1, acc[rg][nt], 0, 0, 0);
            }
        }
    }

    #pragma unroll
    for (int nt = 0; nt < 6; nt++) {
        const int col = NC + nt * 16 + l16;
        const int mat = col >> 7, c = col & 127;
        #pragma unroll
        for (int rg = 0; rg < 2; rg++) {
            const int rowb = R0 + rg * 16 + quad * 4;
            if (mat == 2) {
                const int b = rowb >> 12, s0 = rowb & 4095;
                ushort4 o;                                     // V^T in f16
                o.x = f2h(acc[rg][nt][0]); o.y = f2h(acc[rg][nt][1]);
                o.z = f2h(acc[rg][nt][2]); o.w = f2h(acc[rg][nt][3]);
                *(ushort4*)&Vtws[((size_t)(b * HS + c)) * SEQ + s0] = o;
            } else {
                u16* dst = (mat == 1) ? Qws : Kws;
                #pragma unroll
                for (int r = 0; r < 4; r++)
                    dst[(size_t)(rowb + r) * HS + c] = f2bf(acc[rg][nt][r]);
            }
        }
    }
}

// ---------------- K2: no-LDS no-barrier flash attention ----------------
// grid 32*BATCH*SPLIT x 256. Block: 128 q rows; wave w: rows w*32..+31 (2 qg of 16).
template<int SPLIT>
__global__ __launch_bounds__(256, 2) void attn_kernel(
    const u16* __restrict__ Qws, const u16* __restrict__ Kws,
    const u16* __restrict__ Vtws, u16* __restrict__ Opart,
    float* __restrict__ ml, float* __restrict__ out)
{
    const int tid  = threadIdx.x;
    const int wv   = tid >> 6;
    const int lane = tid & 63;
    const int quad = lane >> 4;
    const int l16  = lane & 15;

    const int L = blockIdx.x;
    const int b = L & 3;
    const int u = L >> 2;
    int Q, sp;
    if constexpr (SPLIT == 1) {
        Q = u; sp = 0;
    } else {
        constexpr int half = SPLIT / 2;
        if (u < 32 * half) { Q = u / half; sp = u % half; }
        else { const int v = u - 32 * half; Q = 31 - v / half; sp = half + v % half; }
    }
    const int q0 = Q * 128;
    const int ktmax = 2 * Q + 1;
    const size_t bS = (size_t)b * SEQ;
    const size_t bH = (size_t)b * HS;

    // Q fragments (B-operand layout: n=q=l16, k=quad*8+j), log2e/sqrt(128) folded
    bf16x8 qf[2][4];
    #pragma unroll
    for (int qg = 0; qg < 2; qg++)
        #pragma unroll
        for (int kf = 0; kf < 4; kf++)
            qf[qg][kf] = *(const bf16x8*)&Qws[(bS + q0 + wv * 32 + qg * 16 + l16) * HS
                                              + kf * 32 + quad * 8];

    float m_i[2], l_i[2];
    f32x4 O[2][8];   // O^T: col=q=l16, row=h=ht*16+quad*4+reg
    #pragma unroll
    for (int qg = 0; qg < 2; qg++) { m_i[qg] = -3.0e38f; l_i[qg] = 0.f; }
    #pragma unroll
    for (int qg = 0; qg < 2; qg++)
        #pragma unroll
        for (int ht = 0; ht < 8; ht++) O[qg][ht] = (f32x4){0.f, 0.f, 0.f, 0.f};

    for (int kt = sp; kt <= ktmax; kt += SPLIT) {
        const int kb = kt * 64;

        // S^T = K·Q^T : D[m=key][n=q]; lane: q=l16, keys=quad*4+r per nt tile
        f32x4 st[2][4];
        #pragma unroll
        for (int qg = 0; qg < 2; qg++)
            #pragma unroll
            for (int nt = 0; nt < 4; nt++) st[qg][nt] = (f32x4){0.f, 0.f, 0.f, 0.f};
        #pragma unroll
        for (int kf = 0; kf < 4; kf++) {
            bf16x8 kfr[4];   // A-frag: m=key=l16, k=quad*8+j — direct from L2
            #pragma unroll
            for (int nt = 0; nt < 4; nt++)
                kfr[nt] = *(const bf16x8*)&Kws[(bS + kb + nt * 16 + l16) * HS
                                               + kf * 32 + quad * 8];
            #pragma unroll
            for (int qg = 0; qg < 2; qg++)
                #pragma unroll
                for (int nt = 0; nt < 4; nt++)
                    st[qg][nt] = __builtin_amdgcn_mfma_f32_16x16x32_bf16(
                        kfr[nt], qf[qg][kf], st[qg][nt], 0, 0, 0);
        }

        const bool diag = (kt >= 2 * Q);
        f16x4 pf[2][4];  // P^T B-frags for 16x16x16f16: n=q=l16, k=key=quad*4+j
        #pragma unroll
        for (int qg = 0; qg < 2; qg++) {
            const int qglob = q0 + wv * 32 + qg * 16 + l16;
            if (diag) {
                #pragma unroll
                for (int nt = 0; nt < 4; nt++)
                    #pragma unroll
                    for (int r = 0; r < 4; r++)
                        if (kb + nt * 16 + quad * 4 + r > qglob) st[qg][nt][r] = -3.0e38f;
            }
            float mx = -3.0e38f;
            #pragma unroll
            for (int nt = 0; nt < 4; nt++)
                #pragma unroll
                for (int r = 0; r < 4; r++) mx = fmaxf(mx, st[qg][nt][r]);
            mx = fmaxf(mx, __shfl_xor(mx, 16));
            mx = fmaxf(mx, __shfl_xor(mx, 32));
            const float mnew = fmaxf(fmaxf(m_i[qg], mx), -1.0e30f);
            const float alpha = exp2f(m_i[qg] - mnew);   // scores already log2-domain
            m_i[qg] = mnew;
            float rs = 0.f;
            #pragma unroll
            for (int nt = 0; nt < 4; nt++)
                #pragma unroll
                for (int r = 0; r < 4; r++) {
                    const float p = exp2f(st[qg][nt][r] - mnew);
                    st[qg][nt][r] = p;
                    rs += p;
                }
            rs += __shfl_xor(rs, 16);
            rs += __shfl_xor(rs, 32);
            l_i[qg] = l_i[qg] * alpha + rs;
            #pragma unroll
            for (int ht = 0; ht < 8; ht++) O[qg][ht] *= alpha;
            #pragma unroll
            for (int nt = 0; nt < 4; nt++) {
                f16x4 p;
                p[0] = (_Float16)st[qg][nt][0]; p[1] = (_Float16)st[qg][nt][1];
                p[2] = (_Float16)st[qg][nt][2]; p[3] = (_Float16)st[qg][nt][3];
                pf[qg][nt] = p;
            }
        }

        // O^T += V^T·P^T : A-frag V^T[h][key] m=h=l16, k=key=quad*4+j — from L2
        #pragma unroll
        for (int ht = 0; ht < 8; ht++) {
            f16x4 vf[4];
            #pragma unroll
            for (int nt = 0; nt < 4; nt++)
                vf[nt] = *(const f16x4*)&Vtws[(bH + ht * 16 + l16) * SEQ
                                              + kb + nt * 16 + quad * 4];
            #pragma unroll
            for (int qg = 0; qg < 2; qg++)
                #pragma unroll
                for (int nt = 0; nt < 4; nt++)
                    O[qg][ht] = __builtin_amdgcn_mfma_f32_16x16x16f16(
                        vf[nt], pf[qg][nt], O[qg][ht], 0, 0, 0);
        }
    }

    if constexpr (SPLIT == 1) {
        #pragma unroll
        for (int qg = 0; qg < 2; qg++) {
            const float inv = 1.0f / l_i[qg];
            const int q = q0 + wv * 32 + qg * 16 + l16;
            #pragma unroll
            for (int ht = 0; ht < 8; ht++) {
                f32x4 o = O[qg][ht] * inv;
                *(f32x4*)&out[(bS + q) * HS + ht * 16 + quad * 4] = o;
            }
        }
    } else {
        const size_t pbase = ((size_t)(sp * BATCH + b)) * SEQ * HS;
        #pragma unroll
        for (int qg = 0; qg < 2; qg++) {
            const int q = q0 + wv * 32 + qg * 16 + l16;
            #pragma unroll
            for (int ht = 0; ht < 8; ht++) {
                ushort4 o;
                o.x = f2bf(O[qg][ht][0]); o.y = f2bf(O[qg][ht][1]);
                o.z = f2bf(O[qg][ht][2]); o.w = f2bf(O[qg][ht][3]);
                *(ushort4*)&Opart[pbase + (size_t)q * HS + ht * 16 + quad * 4] = o;
            }
        }
        if (quad == 0) {
            #pragma unroll
            for (int qg = 0; qg < 2; qg++) {
                const int q = q0 + wv * 32 + qg * 16 + l16;
                float2 v; v.x = m_i[qg]; v.y = l_i[qg];
                *(float2*)&ml[((size_t)(sp * BATCH + b) * SEQ + q) * 2] = v;
            }
        }
    }
}

// ---------------- K3: merge split partials ----------------
template<int SPLIT>
__global__ __launch_bounds__(256) void merge_kernel(
    const u16* __restrict__ Opart, const float* __restrict__ ml,
    float* __restrict__ out)
{
    const int t = threadIdx.x;
    const int gr = blockIdx.x * 8 + (t >> 5);
    const int c4 = (t & 31) * 4;
    const int b = gr >> 12, si = gr & 4095;

    float m[SPLIT], l[SPLIT];
    float M = -3.4e38f;
    #pragma unroll
    for (int s = 0; s < SPLIT; s++) {
        const float2 v = *(const float2*)&ml[((size_t)(s * BATCH + b) * SEQ + si) * 2];
        m[s] = v.x; l[s] = v.y;
        M = fmaxf(M, m[s]);
    }
    float den = 0.f;
    f32x4 num = (f32x4){0.f, 0.f, 0.f, 0.f};
    #pragma unroll
    for (int s = 0; s < SPLIT; s++) {
        const float w = exp2f(m[s] - M);     // m stored in log2 domain
        den += w * l[s];
        const ushort4 o = *(const ushort4*)&Opart[((size_t)(s * BATCH + b) * SEQ + si) * HS + c4];
        num[0] += w * bf2f(o.x); num[1] += w * bf2f(o.y);
        num[2] += w * bf2f(o.z); num[3] += w * bf2f(o.w);
    }
    const float inv = 1.0f / den;
    float4 o; o.x = num[0] * inv; o.y = num[1] * inv; o.z = num[2] * inv; o.w = num[3] * inv;
    *(float4*)&out[(size_t)gr * HS + c4] = o;
}

extern "C" void kernel_launch(void* const* d_in, const int* in_sizes, int n_in,
                              void* d_out, int out_size, void* d_ws, size_t ws_size,
                              hipStream_t stream) {
    const float* emb = (const float*)d_in[0];
    const float* Wk  = (const float*)d_in[1];
    const float* Wq  = (const float*)d_in[2];
    const float* Wv  = (const float*)d_in[3];
    float* out = (float*)d_out;

    char* ws = (char*)d_ws;
    const size_t WBF_SZ    = (size_t)384 * 1024 * 2;
    const size_t QKV_SZ    = (size_t)BATCH * SEQ * HS * 2;
    const size_t Q_OFF     = WBF_SZ;
    const size_t K_OFF     = Q_OFF + QKV_SZ;
    const size_t VT_OFF    = K_OFF + QKV_SZ;
    const size_t OPART_OFF = VT_OFF + QKV_SZ;
    const size_t OPART_1   = (size_t)BATCH * SEQ * HS * 2;
    const size_t ML_1      = (size_t)BATCH * SEQ * 2 * 4;

    u16* Wbf  = (u16*)ws;
    u16* Qws  = (u16*)(ws + Q_OFF);
    u16* Kws  = (u16*)(ws + K_OFF);
    u16* Vtws = (u16*)(ws + VT_OFF);

    const size_t need4 = OPART_OFF + 4 * (OPART_1 + ML_1);
    const size_t need2 = OPART_OFF + 2 * (OPART_1 + ML_1);

    wconv_kernel<<<dim3(384), dim3(256), 0, stream>>>(Wk, Wq, Wv, Wbf);
    qkv_kernel<<<dim3(512), dim3(256), 0, stream>>>(emb, Wbf, Qws, Kws, Vtws);

    if (ws_size >= need4) {
        u16*   Opart = (u16*)(ws + OPART_OFF);
        float* ml    = (float*)(ws + OPART_OFF + 4 * OPART_1);
        attn_kernel<4><<<dim3(32 * BATCH * 4), dim3(256), 0, stream>>>(Qws, Kws, Vtws, Opart, ml, out);
        merge_kernel<4><<<dim3(BATCH * SEQ / 8), dim3(256), 0, stream>>>(Opart, ml, out);
    } else if (ws_size >= need2) {
        u16*   Opart = (u16*)(ws + OPART_OFF);
        float* ml    = (float*)(ws + OPART_OFF + 2 * OPART_1);
        attn_kernel<2><<<dim3(32 * BATCH * 2), dim3(256), 0, stream>>>(Qws, Kws, Vtws, Opart, ml, out);
        merge_kernel<2><<<dim3(BATCH * SEQ / 8), dim3(256), 0, stream>>>(Opart, ml, out);
    } else {
        attn_kernel<1><<<dim3(32 * BATCH), dim3(256), 0, stream>>>(Qws, Kws, Vtws, nullptr, nullptr, out);
    }
}

// Round 7
// 197.453 us; speedup vs baseline: 1.3028x; 1.3028x over previous
//
#include <hip/hip_runtime.h>
#include <hip/hip_bf16.h>

// SingleHeadAttention: embedded [4,4096,1024] f32; Wk/Wq/Wv [128,1024] f32.
// out = causal_softmax((emb Wq^T)(emb Wk^T)^T / sqrt(128)) (emb Wv^T), f32.
//
// R5: coalesced LDS staging + S^T register PV + double-buffer single-barrier.
//  K0 wconv: W f32 -> bf16 pre-tiled in MFMA B-frag order (coalesced qkv loads).
//            Wq prescaled by log2e/sqrt(128).
//  K1 qkv:   GEMM 16384x384x1024, 32 rows/block; A via LDS + reg prefetch;
//            B-frags = contiguous 1KB coalesced loads from Wt. V^T stored f16.
//  K2 attn:  flash causal. K/V^T tiles double-buffered in LDS (coalesced
//            staging, padded rows -> 2-way max). S^T = K·Q^T (C-layout: q=l16,
//            key=quad*4+r) feeds PV directly as B-frag of 16x16x16f16:
//            O^T = V^T·P^T. One barrier per k-tile. Split-K 4/2/1 by ws size.
//  K3 merge: combine split partials (log2-domain m), normalize, f32 out.
// Layout facts (HW-verified R2/R4): mfma D col(lane&15)=B's n, row(quad*4+reg)
// =A's m; A/B frag: index=lane&15, k=quad*8+j (K=32) / quad*4+j (K=16).

#define SEQ 4096
#define BATCH 4
#define HS 128

typedef unsigned short u16;
typedef __bf16 bf16x8 __attribute__((ext_vector_type(8)));
typedef _Float16 f16x4 __attribute__((ext_vector_type(4)));
typedef float f32x4 __attribute__((ext_vector_type(4)));

__device__ __forceinline__ u16 f2bf(float f) {
    union { float f; unsigned u; } v; v.f = f;
    unsigned u = v.u;
    return (u16)((u + 0x7FFFu + ((u >> 16) & 1u)) >> 16);  // RNE, finite
}
__device__ __forceinline__ float bf2f(u16 u) {
    union { unsigned u; float f; } v; v.u = ((unsigned)u) << 16; return v.f;
}
__device__ __forceinline__ u16 f2h(float f) {
    union { _Float16 h; u16 u; } v; v.h = (_Float16)f; return v.u;
}

// ---------------- K0: W -> bf16, pre-tiled in B-frag order ----------------
// Wt group g = ((nt*16 + kc)*2 + kf)*64 + lane holds 8 bf16:
//   W[nt*16 + (lane&15)][kc*64 + kf*32 + (lane>>4)*8 + j]
// row 0-127 = Wk, 128-255 = Wq * log2e/sqrt(128), 256-383 = Wv.
__global__ __launch_bounds__(256) void wconv_kernel(
    const float* __restrict__ Wk, const float* __restrict__ Wq,
    const float* __restrict__ Wv, u16* __restrict__ Wt)
{
    const int g    = blockIdx.x * 256 + threadIdx.x;   // 0..49151
    const int lane = g & 63;
    const int kf   = (g >> 6) & 1;
    const int kc   = (g >> 7) & 15;
    const int nt   = g >> 11;                          // 0..23
    const int row  = nt * 16 + (lane & 15);
    const int k0   = kc * 64 + kf * 32 + (lane >> 4) * 8;
    const float* src = (row < 128) ? Wk : ((row < 256) ? Wq : Wv);
    const float scale = (row >= 128 && row < 256)
        ? 0.08838834764831845f * 1.4426950408889634f : 1.0f;
    const float4 v0 = *(const float4*)&src[(size_t)(row & 127) * 1024 + k0];
    const float4 v1 = *(const float4*)&src[(size_t)(row & 127) * 1024 + k0 + 4];
    ushort4 a, b;
    a.x = f2bf(v0.x * scale); a.y = f2bf(v0.y * scale);
    a.z = f2bf(v0.z * scale); a.w = f2bf(v0.w * scale);
    b.x = f2bf(v1.x * scale); b.y = f2bf(v1.y * scale);
    b.z = f2bf(v1.z * scale); b.w = f2bf(v1.w * scale);
    *(ushort4*)&Wt[(size_t)g * 8]     = a;
    *(ushort4*)&Wt[(size_t)g * 8 + 4] = b;
}

// ---------------- K1: QKV projection ----------------
// grid 512 x 256. Block: 32 emb rows x 384 cols; wave w: cols w*96..+95.
__global__ __launch_bounds__(256, 2) void qkv_kernel(
    const float* __restrict__ emb, const u16* __restrict__ Wt,
    u16* __restrict__ Qws, u16* __restrict__ Kws, u16* __restrict__ Vtws)
{
    __shared__ u16 sE[32][72];

    const int tid  = threadIdx.x;
    const int wv   = tid >> 6;
    const int lane = tid & 63;
    const int quad = lane >> 4;
    const int l16  = lane & 15;
    const int R0   = blockIdx.x * 32;

    f32x4 acc[2][6];
    #pragma unroll
    for (int rg = 0; rg < 2; rg++)
        #pragma unroll
        for (int nt = 0; nt < 6; nt++) acc[rg][nt] = (f32x4){0.f, 0.f, 0.f, 0.f};

    // prefetch chunk 0 into registers
    const int prow = tid >> 4, pc4 = tid & 15;
    const int prow1 = (tid + 256) >> 4, pc41 = (tid + 256) & 15;
    float4 pre0 = *(const float4*)&emb[(size_t)(R0 + prow) * 1024 + pc4 * 4];
    float4 pre1 = *(const float4*)&emb[(size_t)(R0 + prow1) * 1024 + pc41 * 4];

    for (int kci = 0; kci < 16; kci++) {
        __syncthreads();
        {
            ushort4 o;
            o.x = f2bf(pre0.x); o.y = f2bf(pre0.y); o.z = f2bf(pre0.z); o.w = f2bf(pre0.w);
            *(ushort4*)&sE[prow][pc4 * 4] = o;
            o.x = f2bf(pre1.x); o.y = f2bf(pre1.y); o.z = f2bf(pre1.z); o.w = f2bf(pre1.w);
            *(ushort4*)&sE[prow1][pc41 * 4] = o;
        }
        __syncthreads();
        if (kci < 15) {   // prefetch next chunk
            const int kn = (kci + 1) * 64;
            pre0 = *(const float4*)&emb[(size_t)(R0 + prow) * 1024 + kn + pc4 * 4];
            pre1 = *(const float4*)&emb[(size_t)(R0 + prow1) * 1024 + kn + pc41 * 4];
        }

        bf16x8 a[2][2];
        #pragma unroll
        for (int rg = 0; rg < 2; rg++)
            #pragma unroll
            for (int kf = 0; kf < 2; kf++)
                a[rg][kf] = *(const bf16x8*)&sE[rg * 16 + l16][kf * 32 + quad * 8];

        #pragma unroll
        for (int nt = 0; nt < 6; nt++) {
            // coalesced 1KB B-frag loads from pre-tiled Wt
            const size_t gbase = ((size_t)((wv * 6 + nt) * 16 + kci) * 2) * 64 + lane;
            const bf16x8 b0 = *(const bf16x8*)&Wt[gbase * 8];
            const bf16x8 b1 = *(const bf16x8*)&Wt[(gbase + 64) * 8];
            #pragma unroll
            for (int rg = 0; rg < 2; rg++) {
                acc[rg][nt] = __builtin_amdgcn_mfma_f32_16x16x32_bf16(a[rg][0], b0, acc[rg][nt], 0, 0, 0);
                acc[rg][nt] = __builtin_amdgcn_mfma_f32_16x16x32_bf16(a[rg][1], b1, acc[rg][nt], 0, 0, 0);
            }
        }
    }

    #pragma unroll
    for (int nt = 0; nt < 6; nt++) {
        const int col = wv * 96 + nt * 16 + l16;
        const int mat = col >> 7, c = col & 127;
        #pragma unroll
        for (int rg = 0; rg < 2; rg++) {
            const int rowb = R0 + rg * 16 + quad * 4;
            if (mat == 2) {
                const int b = rowb >> 12, s0 = rowb & 4095;
                ushort4 o;                                     // V^T in f16
                o.x = f2h(acc[rg][nt][0]); o.y = f2h(acc[rg][nt][1]);
                o.z = f2h(acc[rg][nt][2]); o.w = f2h(acc[rg][nt][3]);
                *(ushort4*)&Vtws[((size_t)(b * HS + c)) * SEQ + s0] = o;
            } else {
                u16* dst = (mat == 1) ? Qws : Kws;
                #pragma unroll
                for (int r = 0; r < 4; r++)
                    dst[(size_t)(rowb + r) * HS + c] = f2bf(acc[rg][nt][r]);
            }
        }
    }
}

// ---------------- K2: flash attention, dbuf LDS + S^T register PV ----------------
// grid 32*BATCH*SPLIT x 256. Block: 128 q rows; wave w: rows w*32..+31 (2 qg of 16).
template<int SPLIT>
__global__ __launch_bounds__(256, 2) void attn_kernel(
    const u16* __restrict__ Qws, const u16* __restrict__ Kws,
    const u16* __restrict__ Vtws, u16* __restrict__ Opart,
    float* __restrict__ ml, float* __restrict__ out)
{
    __shared__ u16 sK[2][64][136];   // 272B rows: frag reads/writes 2-way max
    __shared__ u16 sV[2][128][72];   // V^T [h][key] f16; 144B rows

    const int tid  = threadIdx.x;
    const int wv   = tid >> 6;
    const int lane = tid & 63;
    const int quad = lane >> 4;
    const int l16  = lane & 15;

    const int L = blockIdx.x;
    const int b = L & 3;
    const int u = L >> 2;
    int Q, sp;
    if constexpr (SPLIT == 1) {
        Q = u; sp = 0;
    } else {
        constexpr int half = SPLIT / 2;
        if (u < 32 * half) { Q = u / half; sp = u % half; }
        else { const int v = u - 32 * half; Q = 31 - v / half; sp = half + v % half; }
    }
    const int q0 = Q * 128;
    const int ktmax = 2 * Q + 1;
    const size_t bS = (size_t)b * SEQ;
    const size_t bH = (size_t)b * HS;

    // staging decomposition (per thread, 4 x 16B each for K and V)
    const int krow = tid >> 4, kc8 = tid & 15;       // K: +i*16 rows
    const int vrow = tid >> 3, vk8 = tid & 7;        // V: +i*32 rows

    // Q fragments (B-operand: n=q=l16, k=quad*8+j), log2e/sqrt(128) folded
    bf16x8 qf[2][4];
    #pragma unroll
    for (int qg = 0; qg < 2; qg++)
        #pragma unroll
        for (int kf = 0; kf < 4; kf++)
            qf[qg][kf] = *(const bf16x8*)&Qws[(bS + q0 + wv * 32 + qg * 16 + l16) * HS
                                              + kf * 32 + quad * 8];

    float m_i[2], l_i[2];
    f32x4 O[2][8];   // O^T: col=q=l16, row=h=ht*16+quad*4+reg
    #pragma unroll
    for (int qg = 0; qg < 2; qg++) { m_i[qg] = -3.0e38f; l_i[qg] = 0.f; }
    #pragma unroll
    for (int qg = 0; qg < 2; qg++)
        #pragma unroll
        for (int ht = 0; ht < 8; ht++) O[qg][ht] = (f32x4){0.f, 0.f, 0.f, 0.f};

    // prologue: stage tile sp into buffer 0
    {
        const int kb = sp * 64;
        #pragma unroll
        for (int i = 0; i < 4; i++)
            *(uint4*)&sK[0][krow + i * 16][kc8 * 8] =
                *(const uint4*)&Kws[(bS + kb + krow + i * 16) * HS + kc8 * 8];
        #pragma unroll
        for (int i = 0; i < 4; i++)
            *(uint4*)&sV[0][vrow + i * 32][vk8 * 8] =
                *(const uint4*)&Vtws[(bH + vrow + i * 32) * SEQ + kb + vk8 * 8];
    }
    __syncthreads();

    int buf = 0;
    for (int kt = sp; kt <= ktmax; kt += SPLIT) {
        const int kb = kt * 64;
        const int nxt = kt + SPLIT;
        const bool more = (nxt <= ktmax);

        // prefetch next tile into registers (in flight during compute)
        uint4 kreg[4], vreg[4];
        if (more) {
            const int nb = nxt * 64;
            #pragma unroll
            for (int i = 0; i < 4; i++)
                kreg[i] = *(const uint4*)&Kws[(bS + nb + krow + i * 16) * HS + kc8 * 8];
            #pragma unroll
            for (int i = 0; i < 4; i++)
                vreg[i] = *(const uint4*)&Vtws[(bH + vrow + i * 32) * SEQ + nb + vk8 * 8];
        }

        // S^T = K·Q^T : D[m=key][n=q]; lane: q=l16, keys=quad*4+r per nt tile
        f32x4 st[2][4];
        #pragma unroll
        for (int qg = 0; qg < 2; qg++)
            #pragma unroll
            for (int nt = 0; nt < 4; nt++) st[qg][nt] = (f32x4){0.f, 0.f, 0.f, 0.f};
        #pragma unroll
        for (int kf = 0; kf < 4; kf++) {
            bf16x8 kfr[4];   // A-frag: m=key=l16, k=quad*8+j — from LDS
            #pragma unroll
            for (int nt = 0; nt < 4; nt++)
                kfr[nt] = *(const bf16x8*)&sK[buf][nt * 16 + l16][kf * 32 + quad * 8];
            #pragma unroll
            for (int qg = 0; qg < 2; qg++)
                #pragma unroll
                for (int nt = 0; nt < 4; nt++)
                    st[qg][nt] = __builtin_amdgcn_mfma_f32_16x16x32_bf16(
                        kfr[nt], qf[qg][kf], st[qg][nt], 0, 0, 0);
        }

        const bool diag = (kt >= 2 * Q);
        f16x4 pf[2][4];  // P^T B-frags for 16x16x16f16: n=q=l16, k=key=quad*4+j
        #pragma unroll
        for (int qg = 0; qg < 2; qg++) {
            const int qglob = q0 + wv * 32 + qg * 16 + l16;
            if (diag) {
                #pragma unroll
                for (int nt = 0; nt < 4; nt++)
                    #pragma unroll
                    for (int r = 0; r < 4; r++)
                        if (kb + nt * 16 + quad * 4 + r > qglob) st[qg][nt][r] = -3.0e38f;
            }
            float mx = -3.0e38f;
            #pragma unroll
            for (int nt = 0; nt < 4; nt++)
                #pragma unroll
                for (int r = 0; r < 4; r++) mx = fmaxf(mx, st[qg][nt][r]);
            mx = fmaxf(mx, __shfl_xor(mx, 16));
            mx = fmaxf(mx, __shfl_xor(mx, 32));
            const float mnew = fmaxf(fmaxf(m_i[qg], mx), -1.0e30f);
            const float alpha = exp2f(m_i[qg] - mnew);   // scores in log2 domain
            m_i[qg] = mnew;
            float rs = 0.f;
            #pragma unroll
            for (int nt = 0; nt < 4; nt++)
                #pragma unroll
                for (int r = 0; r < 4; r++) {
                    const float p = exp2f(st[qg][nt][r] - mnew);
                    st[qg][nt][r] = p;
                    rs += p;
                }
            rs += __shfl_xor(rs, 16);
            rs += __shfl_xor(rs, 32);
            l_i[qg] = l_i[qg] * alpha + rs;
            #pragma unroll
            for (int ht = 0; ht < 8; ht++) O[qg][ht] *= alpha;
            #pragma unroll
            for (int nt = 0; nt < 4; nt++) {
                f16x4 p;
                p[0] = (_Float16)st[qg][nt][0]; p[1] = (_Float16)st[qg][nt][1];
                p[2] = (_Float16)st[qg][nt][2]; p[3] = (_Float16)st[qg][nt][3];
                pf[qg][nt] = p;
            }
        }

        // O^T += V^T·P^T : A-frag V^T[h][key]: m=h=l16, k=key=quad*4+j — from LDS
        #pragma unroll
        for (int ht = 0; ht < 8; ht++) {
            f16x4 vf[4];
            #pragma unroll
            for (int nt = 0; nt < 4; nt++)
                vf[nt] = *(const f16x4*)&sV[buf][ht * 16 + l16][nt * 16 + quad * 4];
            #pragma unroll
            for (int qg = 0; qg < 2; qg++)
                #pragma unroll
                for (int nt = 0; nt < 4; nt++)
                    O[qg][ht] = __builtin_amdgcn_mfma_f32_16x16x16f16(
                        vf[nt], pf[qg][nt], O[qg][ht], 0, 0, 0);
        }

        // write prefetched tile into the other buffer (readers finished last iter)
        if (more) {
            #pragma unroll
            for (int i = 0; i < 4; i++)
                *(uint4*)&sK[buf ^ 1][krow + i * 16][kc8 * 8] = kreg[i];
            #pragma unroll
            for (int i = 0; i < 4; i++)
                *(uint4*)&sV[buf ^ 1][vrow + i * 32][vk8 * 8] = vreg[i];
        }
        __syncthreads();
        buf ^= 1;
    }

    if constexpr (SPLIT == 1) {
        #pragma unroll
        for (int qg = 0; qg < 2; qg++) {
            const float inv = 1.0f / l_i[qg];
            const int q = q0 + wv * 32 + qg * 16 + l16;
            #pragma unroll
            for (int ht = 0; ht < 8; ht++) {
                f32x4 o = O[qg][ht] * inv;
                *(f32x4*)&out[(bS + q) * HS + ht * 16 + quad * 4] = o;
            }
        }
    } else {
        const size_t pbase = ((size_t)(sp * BATCH + b)) * SEQ * HS;
        #pragma unroll
        for (int qg = 0; qg < 2; qg++) {
            const int q = q0 + wv * 32 + qg * 16 + l16;
            #pragma unroll
            for (int ht = 0; ht < 8; ht++) {
                ushort4 o;
                o.x = f2bf(O[qg][ht][0]); o.y = f2bf(O[qg][ht][1]);
                o.z = f2bf(O[qg][ht][2]); o.w = f2bf(O[qg][ht][3]);
                *(ushort4*)&Opart[pbase + (size_t)q * HS + ht * 16 + quad * 4] = o;
            }
        }
        if (quad == 0) {
            #pragma unroll
            for (int qg = 0; qg < 2; qg++) {
                const int q = q0 + wv * 32 + qg * 16 + l16;
                float2 v; v.x = m_i[qg]; v.y = l_i[qg];
                *(float2*)&ml[((size_t)(sp * BATCH + b) * SEQ + q) * 2] = v;
            }
        }
    }
}

// ---------------- K3: merge split partials ----------------
template<int SPLIT>
__global__ __launch_bounds__(256) void merge_kernel(
    const u16* __restrict__ Opart, const float* __restrict__ ml,
    float* __restrict__ out)
{
    const int t = threadIdx.x;
    const int gr = blockIdx.x * 8 + (t >> 5);
    const int c4 = (t & 31) * 4;
    const int b = gr >> 12, si = gr & 4095;

    float m[SPLIT], l[SPLIT];
    float M = -3.4e38f;
    #pragma unroll
    for (int s = 0; s < SPLIT; s++) {
        const float2 v = *(const float2*)&ml[((size_t)(s * BATCH + b) * SEQ + si) * 2];
        m[s] = v.x; l[s] = v.y;
        M = fmaxf(M, m[s]);
    }
    float den = 0.f;
    f32x4 num = (f32x4){0.f, 0.f, 0.f, 0.f};
    #pragma unroll
    for (int s = 0; s < SPLIT; s++) {
        const float w = exp2f(m[s] - M);     // m in log2 domain
        den += w * l[s];
        const ushort4 o = *(const ushort4*)&Opart[((size_t)(s * BATCH + b) * SEQ + si) * HS + c4];
        num[0] += w * bf2f(o.x); num[1] += w * bf2f(o.y);
        num[2] += w * bf2f(o.z); num[3] += w * bf2f(o.w);
    }
    const float inv = 1.0f / den;
    float4 o; o.x = num[0] * inv; o.y = num[1] * inv; o.z = num[2] * inv; o.w = num[3] * inv;
    *(float4*)&out[(size_t)gr * HS + c4] = o;
}

extern "C" void kernel_launch(void* const* d_in, const int* in_sizes, int n_in,
                              void* d_out, int out_size, void* d_ws, size_t ws_size,
                              hipStream_t stream) {
    const float* emb = (const float*)d_in[0];
    const float* Wk  = (const float*)d_in[1];
    const float* Wq  = (const float*)d_in[2];
    const float* Wv  = (const float*)d_in[3];
    float* out = (float*)d_out;

    char* ws = (char*)d_ws;
    const size_t WBF_SZ    = (size_t)384 * 1024 * 2;
    const size_t QKV_SZ    = (size_t)BATCH * SEQ * HS * 2;
    const size_t Q_OFF     = WBF_SZ;
    const size_t K_OFF     = Q_OFF + QKV_SZ;
    const size_t VT_OFF    = K_OFF + QKV_SZ;
    const size_t OPART_OFF = VT_OFF + QKV_SZ;
    const size_t OPART_1   = (size_t)BATCH * SEQ * HS * 2;
    const size_t ML_1      = (size_t)BATCH * SEQ * 2 * 4;

    u16* Wt   = (u16*)ws;
    u16* Qws  = (u16*)(ws + Q_OFF);
    u16* Kws  = (u16*)(ws + K_OFF);
    u16* Vtws = (u16*)(ws + VT_OFF);

    const size_t need4 = OPART_OFF + 4 * (OPART_1 + ML_1);
    const size_t need2 = OPART_OFF + 2 * (OPART_1 + ML_1);

    wconv_kernel<<<dim3(192), dim3(256), 0, stream>>>(Wk, Wq, Wv, Wt);
    qkv_kernel<<<dim3(512), dim3(256), 0, stream>>>(emb, Wt, Qws, Kws, Vtws);

    if (ws_size >= need4) {
        u16*   Opart = (u16*)(ws + OPART_OFF);
        float* ml    = (float*)(ws + OPART_OFF + 4 * OPART_1);
        attn_kernel<4><<<dim3(32 * BATCH * 4), dim3(256), 0, stream>>>(Qws, Kws, Vtws, Opart, ml, out);
        merge_kernel<4><<<dim3(BATCH * SEQ / 8), dim3(256), 0, stream>>>(Opart, ml, out);
    } else if (ws_size >= need2) {
        u16*   Opart = (u16*)(ws + OPART_OFF);
        float* ml    = (float*)(ws + OPART_OFF + 2 * OPART_1);
        attn_kernel<2><<<dim3(32 * BATCH * 2), dim3(256), 0, stream>>>(Qws, Kws, Vtws, Opart, ml, out);
        merge_kernel<2><<<dim3(BATCH * SEQ / 8), dim3(256), 0, stream>>>(Opart, ml, out);
    } else {
        attn_kernel<1><<<dim3(32 * BATCH), dim3(256), 0, stream>>>(Qws, Kws, Vtws, nullptr, nullptr, out);
    }
}